// Round 1
// baseline (245.764 us; speedup 1.0000x reference)
//
#include <hip/hip_runtime.h>
#include <hip/hip_bf16.h>

// CRF NLL + argmax for B=2048, T=1024, K=8.
// Strategy: exp-space chunked forward algorithm.
//   p_t = D_t * E^T * p_{t-1},  E = exp(transitions), D_t = diag(exp(score_t))
//   T split into NC=16 chunks of CL=64; each chunk's 8x8 transfer matrix is
//   computed by 8 threads (one column each) with per-column log-scales
//   (rescale every 8 steps). Combine kernel folds chunks into p0 per batch.
// Workspace use: B*NC*64 (matrices) + B*NC*8 (scales) + B (numerator) floats
// = ~9.4 MB.

namespace {

constexpr int B = 2048;
constexpr int T = 1024;
constexpr int K = 8;
constexpr int CL = 64;
constexpr int NC = T / CL;  // 16

__device__ __forceinline__ float max8(const float* a) {
  return fmaxf(fmaxf(fmaxf(a[0], a[1]), fmaxf(a[2], a[3])),
               fmaxf(fmaxf(a[4], a[5]), fmaxf(a[6], a[7])));
}

// ---------------------------------------------------------------------------
// Kernel 1: per-(b,t) argmax prediction + gold-path numerator partials.
// One thread per (b,t); a 64-lane wave covers 64 consecutive t of one batch.
// ---------------------------------------------------------------------------
__global__ __launch_bounds__(256) void pred_num_kernel(
    const float* __restrict__ log_p, const float* __restrict__ score,
    const float* __restrict__ trans, const float* __restrict__ start_tr,
    const float* __restrict__ end_tr, const int* __restrict__ tags,
    const int* __restrict__ seq_l, float* __restrict__ out_pred,
    float* __restrict__ ws_num) {
  int g = blockIdx.x * blockDim.x + threadIdx.x;  // g = b*T + t
  int b = g >> 10;
  int t = g & (T - 1);

  const float4* lp = reinterpret_cast<const float4*>(log_p) + (g << 1);
  float4 u0 = lp[0], u1 = lp[1];
  float v[8] = {u0.x, u0.y, u0.z, u0.w, u1.x, u1.y, u1.z, u1.w};
  int best = 0;
  float bv = v[0];
#pragma unroll
  for (int j = 1; j < 8; ++j) {
    if (v[j] > bv) { bv = v[j]; best = j; }  // strict > keeps first max (jnp.argmax)
  }

  int L = seq_l[b];
  bool act = (t < L);
  out_pred[g] = act ? (float)best : 0.0f;

  // numerator: emit*mask + start (t==0) + trans (t>=1, masked) + end (t==L-1)
  float contrib = 0.0f;
  if (act) {
    int tg = tags[g];
    contrib = score[g * 8 + tg];
    if (t == 0)
      contrib += start_tr[tg];
    else
      contrib += trans[tags[g - 1] * 8 + tg];
    if (t == L - 1) contrib += end_tr[tg];
  }
#pragma unroll
  for (int off = 32; off >= 1; off >>= 1) contrib += __shfl_down(contrib, off);
  if ((threadIdx.x & 63) == 0) atomicAdd(&ws_num[b], contrib);
}

// ---------------------------------------------------------------------------
// Kernel 2: chunk transfer matrices. thread -> (b, c, k): column k of the
// 8x8 product  A_c = M_{te-1} ... M_{ts},  M_t = diag(exp(emit_t)) * E^T.
// Stored as normalized column (max entry 1) + per-column log-scale.
// Chunks fully beyond seq_l are the identity.
// ---------------------------------------------------------------------------
__global__ __launch_bounds__(256) void chunk_kernel(
    const float* __restrict__ score, const float* __restrict__ trans,
    const int* __restrict__ seq_l, float* __restrict__ wsA,
    float* __restrict__ wsS) {
  int g = blockIdx.x * blockDim.x + threadIdx.x;
  int k = g & 7;
  int c = (g >> 3) & (NC - 1);
  int b = g >> 7;

  // E[i][j] = exp(transitions[i][j]); uniform loads, fully unrolled -> regs
  float E[8][8];
#pragma unroll
  for (int i = 0; i < 8; ++i)
#pragma unroll
    for (int j = 0; j < 8; ++j) E[i][j] = __expf(trans[i * 8 + j]);

  float a[8];
#pragma unroll
  for (int j = 0; j < 8; ++j) a[j] = (j == k) ? 1.0f : 0.0f;
  float sig = 0.0f;

  int L = seq_l[b];
  int t0 = c * CL;
  int ts = (c == 0) ? 1 : t0;  // step t=0 handled as p0 in combine
  int te = min(t0 + CL, L);
  int n = te - ts;
  const float* sp = score + ((size_t)b * T + ts) * 8;

  for (int it = 0; it < n; ++it) {
    float4 sA = *reinterpret_cast<const float4*>(sp);
    float4 sB = *reinterpret_cast<const float4*>(sp + 4);
    sp += 8;
    float em[8] = {__expf(sA.x), __expf(sA.y), __expf(sA.z), __expf(sA.w),
                   __expf(sB.x), __expf(sB.y), __expf(sB.z), __expf(sB.w)};
    float na[8];
#pragma unroll
    for (int j = 0; j < 8; ++j) {
      float acc = E[0][j] * a[0];
#pragma unroll
      for (int i = 1; i < 8; ++i) acc = fmaf(E[i][j], a[i], acc);
      na[j] = em[j] * acc;
    }
#pragma unroll
    for (int j = 0; j < 8; ++j) a[j] = na[j];
    // growth per step <= ~2^12.3 worst case -> rescale every 8 steps is safe
    if ((it & 7) == 7) {
      float mm = max8(a);
      float r = __builtin_amdgcn_rcpf(mm);
#pragma unroll
      for (int j = 0; j < 8; ++j) a[j] *= r;
      sig += __logf(mm);
    }
  }
  {  // final normalize (identity case: mm==1, sig stays 0)
    float mm = max8(a);
    if (mm > 0.0f) {
      float r = __builtin_amdgcn_rcpf(mm);
#pragma unroll
      for (int j = 0; j < 8; ++j) a[j] *= r;
      sig += __logf(mm);
    }
  }

  float* Ao = wsA + (size_t)(((b * NC + c) * 8 + k) * 8);
  *reinterpret_cast<float4*>(Ao) = make_float4(a[0], a[1], a[2], a[3]);
  *reinterpret_cast<float4*>(Ao + 4) = make_float4(a[4], a[5], a[6], a[7]);
  wsS[(b * NC + c) * 8 + k] = sig;
}

// ---------------------------------------------------------------------------
// Kernel 3: per-batch combine: p0 = exp(start + score[b,0,:]), then
// p <- A_c * diag(exp(sigma_col)) * p for c = 0..NC-1 (scale-aware),
// log_z = tau + log(sum_j p_j * exp(end_j)); loss partial reduced to d_out[0].
// ---------------------------------------------------------------------------
__global__ __launch_bounds__(256) void combine_kernel(
    const float* __restrict__ score, const float* __restrict__ start_tr,
    const float* __restrict__ end_tr, const float* __restrict__ wsA,
    const float* __restrict__ wsS, const float* __restrict__ ws_num,
    float* __restrict__ out_loss) {
  int b = blockIdx.x * blockDim.x + threadIdx.x;

  const float* s0 = score + (size_t)b * T * 8;
  float p[8];
#pragma unroll
  for (int j = 0; j < 8; ++j) p[j] = __expf(start_tr[j] + s0[j]);
  float tau = 0.0f;
  {
    float mm = max8(p);
    float r = __builtin_amdgcn_rcpf(mm);
#pragma unroll
    for (int j = 0; j < 8; ++j) p[j] *= r;
    tau += __logf(mm);
  }

  float een[8];
#pragma unroll
  for (int j = 0; j < 8; ++j) een[j] = __expf(end_tr[j]);

  for (int c = 0; c < NC; ++c) {
    const float* Ab = wsA + (size_t)((b * NC + c) * 64);
    const float* Sb = wsS + (b * NC + c) * 8;
    float sg[8];
#pragma unroll
    for (int j = 0; j < 8; ++j) sg[j] = Sb[j];
    float smax = max8(sg);
    float w[8];
#pragma unroll
    for (int j = 0; j < 8; ++j) w[j] = p[j] * __expf(sg[j] - smax);

    float Am[8][8];  // Am[i][j] = A[j][i] (column i contiguous)
#pragma unroll
    for (int i = 0; i < 8; ++i) {
      float4 q0 = *reinterpret_cast<const float4*>(Ab + i * 8);
      float4 q1 = *reinterpret_cast<const float4*>(Ab + i * 8 + 4);
      Am[i][0] = q0.x; Am[i][1] = q0.y; Am[i][2] = q0.z; Am[i][3] = q0.w;
      Am[i][4] = q1.x; Am[i][5] = q1.y; Am[i][6] = q1.z; Am[i][7] = q1.w;
    }
    float np[8];
#pragma unroll
    for (int j = 0; j < 8; ++j) {
      float acc = Am[0][j] * w[0];
#pragma unroll
      for (int i = 1; i < 8; ++i) acc = fmaf(Am[i][j], w[i], acc);
      np[j] = acc;
    }
    tau += smax;
    float mm = max8(np);
    float r = __builtin_amdgcn_rcpf(mm);
#pragma unroll
    for (int j = 0; j < 8; ++j) p[j] = np[j] * r;
    tau += __logf(mm);
  }

  float acc = 0.0f;
#pragma unroll
  for (int j = 0; j < 8; ++j) acc = fmaf(p[j], een[j], acc);
  float logz = tau + __logf(acc);

  float part = (logz - ws_num[b]) * (1.0f / (float)B);
#pragma unroll
  for (int off = 32; off >= 1; off >>= 1) part += __shfl_down(part, off);
  if ((threadIdx.x & 63) == 0) atomicAdd(out_loss, part);
}

}  // namespace

extern "C" void kernel_launch(void* const* d_in, const int* in_sizes, int n_in,
                              void* d_out, int out_size, void* d_ws,
                              size_t ws_size, hipStream_t stream) {
  const float* log_p = (const float*)d_in[0];
  const float* score = (const float*)d_in[1];
  const float* trans = (const float*)d_in[2];
  const float* start_tr = (const float*)d_in[3];
  const float* end_tr = (const float*)d_in[4];
  const int* tags = (const int*)d_in[5];
  const int* seq_l = (const int*)d_in[6];
  float* out = (float*)d_out;  // out[0] = loss, out[1..] = pred_idx (as f32)

  float* wsA = (float*)d_ws;                    // B*NC*64 floats
  float* wsS = wsA + (size_t)B * NC * 64;       // B*NC*8 floats
  float* wsNum = wsS + (size_t)B * NC * 8;      // B floats

  hipMemsetAsync(wsNum, 0, B * sizeof(float), stream);
  hipMemsetAsync(out, 0, sizeof(float), stream);

  pred_num_kernel<<<(B * T) / 256, 256, 0, stream>>>(
      log_p, score, trans, start_tr, end_tr, tags, seq_l, out + 1, wsNum);
  chunk_kernel<<<(B * NC * 8) / 256, 256, 0, stream>>>(score, trans, seq_l,
                                                       wsA, wsS);
  combine_kernel<<<B / 256, 256, 0, stream>>>(score, start_tr, end_tr, wsA,
                                              wsS, wsNum, out);
}

// Round 2
// 220.823 us; speedup vs baseline: 1.1129x; 1.1129x over previous
//
#include <hip/hip_runtime.h>
#include <hip/hip_bf16.h>

// CRF NLL + argmax for B=2048, T=1024, K=8.
// Exp-space chunked forward algorithm:
//   p_t = D_t * E^T * p_{t-1},  E = exp(transitions), D_t = diag(exp(score_t))
// T split into NC chunks; each chunk's 8x8 transfer matrix computed by 8
// threads (one column each) with per-column log-scales. Matrices stored
// ROW-major so the combine kernel (8 lanes per batch, lane j = output row j)
// reads its row with 2 coalesced float4 loads; w is all-gathered with
// width-8 shuffles.

namespace {

constexpr int B = 2048;
constexpr int T = 1024;

__device__ __forceinline__ float max8(const float* a) {
  return fmaxf(fmaxf(fmaxf(a[0], a[1]), fmaxf(a[2], a[3])),
               fmaxf(fmaxf(a[4], a[5]), fmaxf(a[6], a[7])));
}

// ---------------------------------------------------------------------------
// Kernel 1: per-(b,t) argmax prediction + gold-path numerator partials.
// ---------------------------------------------------------------------------
__global__ __launch_bounds__(256) void pred_num_kernel(
    const float* __restrict__ log_p, const float* __restrict__ score,
    const float* __restrict__ trans, const float* __restrict__ start_tr,
    const float* __restrict__ end_tr, const int* __restrict__ tags,
    const int* __restrict__ seq_l, float* __restrict__ out_pred,
    float* __restrict__ ws_num) {
  int g = blockIdx.x * blockDim.x + threadIdx.x;  // g = b*T + t
  int b = g >> 10;
  int t = g & (T - 1);

  const float4* lp = reinterpret_cast<const float4*>(log_p) + (g << 1);
  float4 u0 = lp[0], u1 = lp[1];
  float v[8] = {u0.x, u0.y, u0.z, u0.w, u1.x, u1.y, u1.z, u1.w};
  int best = 0;
  float bv = v[0];
#pragma unroll
  for (int j = 1; j < 8; ++j) {
    if (v[j] > bv) { bv = v[j]; best = j; }  // strict > == first max (argmax)
  }

  int L = seq_l[b];
  bool act = (t < L);
  out_pred[g] = act ? (float)best : 0.0f;

  float contrib = 0.0f;
  if (act) {
    int tg = tags[g];
    contrib = score[g * 8 + tg];
    if (t == 0)
      contrib += start_tr[tg];
    else
      contrib += trans[tags[g - 1] * 8 + tg];
    if (t == L - 1) contrib += end_tr[tg];
  }
#pragma unroll
  for (int off = 32; off >= 1; off >>= 1) contrib += __shfl_down(contrib, off);
  if ((threadIdx.x & 63) == 0) atomicAdd(&ws_num[b], contrib);
}

// ---------------------------------------------------------------------------
// Kernel 2: chunk transfer matrices. thread -> (b, c, k): column k of
// A_c = M_{te-1} ... M_{ts}. Stored ROW-major: wsA[(b,c)*64 + j*8 + k].
// ---------------------------------------------------------------------------
template <int NC>
__global__ __launch_bounds__(256) void chunk_kernel(
    const float* __restrict__ score, const float* __restrict__ trans,
    const int* __restrict__ seq_l, float* __restrict__ wsA,
    float* __restrict__ wsS) {
  constexpr int CL = T / NC;
  int g = blockIdx.x * blockDim.x + threadIdx.x;
  int k = g & 7;
  int c = (g >> 3) & (NC - 1);
  int b = g >> 3 >> /*log2(NC)*/ (NC == 32 ? 5 : 4);

  float E[8][8];
#pragma unroll
  for (int i = 0; i < 8; ++i)
#pragma unroll
    for (int j = 0; j < 8; ++j) E[i][j] = __expf(trans[i * 8 + j]);

  float a[8];
#pragma unroll
  for (int j = 0; j < 8; ++j) a[j] = (j == k) ? 1.0f : 0.0f;
  float sig = 0.0f;

  int L = seq_l[b];
  int t0 = c * CL;
  int ts = (c == 0) ? 1 : t0;  // t=0 folded into p0 in combine
  int te = min(t0 + CL, L);
  int n = te - ts;
  const float* sp = score + ((size_t)b * T + ts) * 8;

  for (int it = 0; it < n; ++it) {
    float4 sA = *reinterpret_cast<const float4*>(sp);
    float4 sB = *reinterpret_cast<const float4*>(sp + 4);
    sp += 8;
    float em[8] = {__expf(sA.x), __expf(sA.y), __expf(sA.z), __expf(sA.w),
                   __expf(sB.x), __expf(sB.y), __expf(sB.z), __expf(sB.w)};
    float na[8];
#pragma unroll
    for (int j = 0; j < 8; ++j) {
      float acc = E[0][j] * a[0];
#pragma unroll
      for (int i = 1; i < 8; ++i) acc = fmaf(E[i][j], a[i], acc);
      na[j] = em[j] * acc;
    }
#pragma unroll
    for (int j = 0; j < 8; ++j) a[j] = na[j];
    if ((it & 7) == 7) {
      float mm = max8(a);
      float r = __builtin_amdgcn_rcpf(mm);
#pragma unroll
      for (int j = 0; j < 8; ++j) a[j] *= r;
      sig += __logf(mm);
    }
  }
  {
    float mm = max8(a);
    if (mm > 0.0f) {
      float r = __builtin_amdgcn_rcpf(mm);
#pragma unroll
      for (int j = 0; j < 8; ++j) a[j] *= r;
      sig += __logf(mm);
    }
  }

  float* Ao = wsA + (size_t)(b * NC + c) * 64;
#pragma unroll
  for (int j = 0; j < 8; ++j) Ao[j * 8 + k] = a[j];  // row-major
  wsS[(b * NC + c) * 8 + k] = sig;
}

// ---------------------------------------------------------------------------
// Kernel 3: combine, 8 lanes per batch. Lane j owns output row j:
//   np[j] = sum_i A[j][i] * w[i],  w[i] = p[i]*exp(sig[i]-smax)
// w/np all-gathered & max-reduced with width-8 shuffles.
// ---------------------------------------------------------------------------
template <int NC>
__global__ __launch_bounds__(256) void combine_kernel(
    const float* __restrict__ score, const float* __restrict__ start_tr,
    const float* __restrict__ end_tr, const float* __restrict__ wsA,
    const float* __restrict__ wsS, const float* __restrict__ ws_num,
    float* __restrict__ out_loss) {
  int tid = blockIdx.x * blockDim.x + threadIdx.x;
  int j = tid & 7;
  int b = tid >> 3;

  float pj = __expf(start_tr[j] + score[(size_t)b * T * 8 + j]);
  float mm = pj;
#pragma unroll
  for (int m = 1; m < 8; m <<= 1) mm = fmaxf(mm, __shfl_xor(mm, m, 8));
  float tau = __logf(mm);
  pj *= __builtin_amdgcn_rcpf(mm);

  float eej = __expf(end_tr[j]);

  for (int c = 0; c < NC; ++c) {
    const float* Ab = wsA + (size_t)(b * NC + c) * 64;
    float sgj = wsS[(b * NC + c) * 8 + j];
    float smax = sgj;
#pragma unroll
    for (int m = 1; m < 8; m <<= 1) smax = fmaxf(smax, __shfl_xor(smax, m, 8));
    float wj = pj * __expf(sgj - smax);
    float w[8];
#pragma unroll
    for (int i = 0; i < 8; ++i) w[i] = __shfl(wj, i, 8);
    float4 r0 = *reinterpret_cast<const float4*>(Ab + j * 8);
    float4 r1 = *reinterpret_cast<const float4*>(Ab + j * 8 + 4);
    float acc = r0.x * w[0];
    acc = fmaf(r0.y, w[1], acc);
    acc = fmaf(r0.z, w[2], acc);
    acc = fmaf(r0.w, w[3], acc);
    acc = fmaf(r1.x, w[4], acc);
    acc = fmaf(r1.y, w[5], acc);
    acc = fmaf(r1.z, w[6], acc);
    acc = fmaf(r1.w, w[7], acc);
    float mm2 = acc;
#pragma unroll
    for (int m = 1; m < 8; m <<= 1) mm2 = fmaxf(mm2, __shfl_xor(mm2, m, 8));
    tau += smax + __logf(mm2);
    pj = acc * __builtin_amdgcn_rcpf(mm2);
  }

  float term = pj * eej;
#pragma unroll
  for (int m = 1; m < 8; m <<= 1) term += __shfl_xor(term, m, 8);
  float logz = tau + __logf(term);

  float part = (j == 0) ? (logz - ws_num[b]) * (1.0f / (float)B) : 0.0f;
#pragma unroll
  for (int off = 32; off >= 1; off >>= 1) part += __shfl_down(part, off);
  if ((threadIdx.x & 63) == 0) atomicAdd(out_loss, part);
}

}  // namespace

extern "C" void kernel_launch(void* const* d_in, const int* in_sizes, int n_in,
                              void* d_out, int out_size, void* d_ws,
                              size_t ws_size, hipStream_t stream) {
  const float* log_p = (const float*)d_in[0];
  const float* score = (const float*)d_in[1];
  const float* trans = (const float*)d_in[2];
  const float* start_tr = (const float*)d_in[3];
  const float* end_tr = (const float*)d_in[4];
  const int* tags = (const int*)d_in[5];
  const int* seq_l = (const int*)d_in[6];
  float* out = (float*)d_out;  // out[0] = loss, out[1..] = pred_idx (as f32)

  // Workspace for NC chunks: A = B*NC*64, S = B*NC*8, num = B floats.
  size_t need32 = ((size_t)B * 32 * 72 + B) * sizeof(float);
  bool use32 = ws_size >= need32;
  int nc = use32 ? 32 : 16;

  float* wsA = (float*)d_ws;                        // B*nc*64
  float* wsS = wsA + (size_t)B * nc * 64;           // B*nc*8
  float* wsNum = wsS + (size_t)B * nc * 8;          // B

  hipMemsetAsync(wsNum, 0, B * sizeof(float), stream);
  hipMemsetAsync(out, 0, sizeof(float), stream);

  pred_num_kernel<<<(B * T) / 256, 256, 0, stream>>>(
      log_p, score, trans, start_tr, end_tr, tags, seq_l, out + 1, wsNum);
  if (use32) {
    chunk_kernel<32><<<(B * 32 * 8) / 256, 256, 0, stream>>>(score, trans,
                                                             seq_l, wsA, wsS);
    combine_kernel<32><<<(B * 8) / 256, 256, 0, stream>>>(
        score, start_tr, end_tr, wsA, wsS, wsNum, out);
  } else {
    chunk_kernel<16><<<(B * 16 * 8) / 256, 256, 0, stream>>>(score, trans,
                                                             seq_l, wsA, wsS);
    combine_kernel<16><<<(B * 8) / 256, 256, 0, stream>>>(
        score, start_tr, end_tr, wsA, wsS, wsNum, out);
  }
}